// Round 10
// baseline (9457.657 us; speedup 1.0000x reference)
//
#include <hip/hip_runtime.h>
#include <math.h>

constexpr int kB  = 128;
constexpr int kT  = 1024;
constexpr int kD  = 32;
constexpr int kH  = 64;
constexpr int kW  = 128;
constexpr int kC  = kD + 1;    // 33
constexpr int kO  = kH * kC;   // 2112
constexpr int kIN = kH + 1;    // 65
constexpr int RPS = 528;       // rows per h-slice (16 h * 33 c)

// ---- workspace layout (u32 units); [0,149952) identical to proven R4 ----
constexpr int WS_W2    = 0;          // 135168 u32, tiled: (((row>>6)*16+q)*64+(row&63))*4+e
constexpr int WS_W1    = 135168;     // 8192 u32
constexpr int WS_W0    = 143360;     // 4224 u32
constexpr int WS_SC2   = 147584;     // 2112 f32
constexpr int WS_SC1   = 149696;     // 128
constexpr int WS_SC0   = 149824;     // 128
constexpr int WS_R4TOT = 149952;
constexpr int WS_FLAG  = 149952;     // 1 u32 rescue flag
constexpr int WS_XCH   = 149954;     // u64[16384]: 64 grp * 4 slice * 2 parity * 32
constexpr int WS_TOT   = 182724;     // 730,896 B

__device__ __forceinline__ float fast_sigmoid(float x) { return 1.0f / (1.0f + __expf(-x)); }
__device__ __forceinline__ float lipswish_f(float x)   { return 0.909f * x * fast_sigmoid(x); }
__device__ __forceinline__ float fast_tanh(float x) {
    float ax = fabsf(x);
    float e  = __expf(2.0f * ax);
    float r  = 1.0f - 2.0f / (e + 1.0f);
    return copysignf(r, x);
}
__device__ __forceinline__ float dot4(float4 a, float4 b) {
    return a.x * b.x + a.y * b.y + a.z * b.z + a.w * b.w;
}
__device__ __forceinline__ float fma2i(unsigned u, float z0, float z1, float acc) {
    int lo = (int)(short)(u & 0xffffu);
    int hi = ((int)u) >> 16;
    acc += (float)lo * z0 + (float)hi * z1;
    return acc;
}
__device__ __forceinline__ float fma8i(uint4 u, float4 zl, float4 zh, float acc) {
    acc = fma2i(u.x, zl.x, zl.y, acc);
    acc = fma2i(u.y, zl.z, zl.w, acc);
    acc = fma2i(u.z, zh.x, zh.y, acc);
    acc = fma2i(u.w, zh.z, zh.w, acc);
    return acc;
}
__device__ __forceinline__ int q15(float w, float inv) {
    float q = rintf(w * inv);
    q = fmaxf(-32767.0f, fminf(32767.0f, q));
    return (int)q;
}
__device__ __forceinline__ unsigned pack16(int a, int b) {
    return ((unsigned)a & 0xffffu) | ((unsigned)b << 16);
}

// one wave per row: [0,2112) W2 tiled, then W1, W0
__global__ __launch_bounds__(64)
void prep_kernel(const float* __restrict__ vW0, const float* __restrict__ vW1,
                 const float* __restrict__ vW2, unsigned* __restrict__ ws, int zflag)
{
    const int row  = blockIdx.x;
    const int lane = threadIdx.x;
    float* scf = (float*)ws;

    if (zflag && row == 0 && lane == 0) ws[WS_FLAG] = 0;

    if (row < kO) {
        const float* src = vW2 + (size_t)row * kW;
        float m = fmaxf(fabsf(src[lane]), fabsf(src[lane + 64]));
        #pragma unroll
        for (int s = 1; s < 64; s <<= 1) m = fmaxf(m, __shfl_xor(m, s));
        float inv = (m > 0.0f) ? 32767.0f / m : 0.0f;
        if (lane == 0) scf[WS_SC2 + row] = (m > 0.0f) ? m / 32767.0f : 0.0f;
        int w = lane;
        unsigned pk = pack16(q15(src[2 * w], inv), q15(src[2 * w + 1], inv));
        int R = row >> 6, r = row & 63, q = w >> 2, e = w & 3;
        ws[WS_W2 + (((R * 16 + q) * 64 + r) << 2) + e] = pk;
    } else if (row < kO + kW) {
        int r = row - kO;
        const float* src = vW1 + (size_t)r * kW;
        float m = fmaxf(fabsf(src[lane]), fabsf(src[lane + 64]));
        #pragma unroll
        for (int s = 1; s < 64; s <<= 1) m = fmaxf(m, __shfl_xor(m, s));
        float inv = (m > 0.0f) ? 32767.0f / m : 0.0f;
        if (lane == 0) scf[WS_SC1 + r] = (m > 0.0f) ? m / 32767.0f : 0.0f;
        ws[WS_W1 + r * 64 + lane] =
            pack16(q15(src[2 * lane], inv), q15(src[2 * lane + 1], inv));
    } else {
        int r = row - kO - kW;
        const float* src = vW0 + (size_t)r * kIN;
        float m = fabsf(src[lane]);
        if (lane == 0) m = fmaxf(m, fabsf(src[64]));
        #pragma unroll
        for (int s = 1; s < 64; s <<= 1) m = fmaxf(m, __shfl_xor(m, s));
        float inv = (m > 0.0f) ? 32767.0f / m : 0.0f;
        if (lane == 0) scf[WS_SC0 + r] = (m > 0.0f) ? m / 32767.0f : 0.0f;
        if (lane < 33) {
            int c0 = 2 * lane, c1 = 2 * lane + 1;
            int qa = q15(src[c0], inv);
            int qb = (c1 < kIN) ? q15(src[c1], inv) : 0;
            ws[WS_W0 + r * 33 + lane] = pack16(qa, qb);
        }
    }
}

// tagged u64 exchange helpers: hi = epoch tag, lo = float bits
__device__ __forceinline__ void xput(unsigned long long* slot, unsigned tag, float v) {
    unsigned long long pk = ((unsigned long long)tag << 32) |
                            (unsigned long long)__float_as_uint(v);
    __hip_atomic_store(slot, pk, __ATOMIC_RELAXED, __HIP_MEMORY_SCOPE_AGENT);
}
__device__ __forceinline__ float xget(unsigned long long* slot, unsigned tag,
                                      int& budget, int& flagged, unsigned* flag) {
    unsigned long long v = __hip_atomic_load(slot, __ATOMIC_RELAXED,
                                             __HIP_MEMORY_SCOPE_AGENT);
    while ((unsigned)(v >> 32) != tag && budget > 0) {
        --budget;
        __builtin_amdgcn_s_sleep(1);
        v = __hip_atomic_load(slot, __ATOMIC_RELAXED, __HIP_MEMORY_SCOPE_AGENT);
    }
    if ((unsigned)(v >> 32) != tag && !flagged) {
        flagged = 1;
        atomicOr(flag, 1u);     // rescue kernel will recompute everything
    }
    return __uint_as_float((unsigned)v);
}

// ============ sliced kernel: 256 blocks, W2 slice LDS-resident ============
// group g = blk&63 (batches 2g,2g+1), slice s = blk>>6 (h in [16s,16s+16))
__global__ __launch_bounds__(1024)
void cde_sliced(
    const float* __restrict__ ts,  const float* __restrict__ ys,
    const float* __restrict__ iW0, const float* __restrict__ ib0,
    const float* __restrict__ iW1, const float* __restrict__ ib1,
    const float* __restrict__ iW2, const float* __restrict__ ib2,
    const float* __restrict__ vb0, const float* __restrict__ vb1,
    const float* __restrict__ vb2,
    const float* __restrict__ rW,  const float* __restrict__ rb,
    unsigned* __restrict__ wsb, float* __restrict__ out)
{
    const int blk = blockIdx.x;
    const int t   = threadIdx.x;
    const int g   = blk & 63;
    const int s   = blk >> 6;

    extern __shared__ unsigned s_w2[];   // 135,168 B: uint4 [chunk q][row]
    __shared__ __align__(16) float s_z1[2][kW], s_z2[2][kW];
    __shared__ __align__(16) float s_inp[2][68];     // [65..67] = 0 pad
    __shared__ float s_v[2][RPS];
    __shared__ float s_y[2][16], s_yh[2][16], s_e[2][16];
    __shared__ float s_dx[2][2][34];
    __shared__ float s_yt[2][kH];

    const float*        scf   = (const float*)wsb;
    const unsigned*     wsW1  = wsb + WS_W1;
    const unsigned*     wsW0  = wsb + WS_W0;
    unsigned long long* xch   = (unsigned long long*)(wsb + WS_XCH);
    unsigned*           flagp = wsb + WS_FLAG;

    const int jj_ = t >> 9;
    const int r_  = (t >> 2) & 127;
    const int k4_ = t & 3;
    const float b0r = vb0[r_], s0r = scf[WS_SC0 + r_];
    const float b1r = vb1[r_], s1r = scf[WS_SC1 + r_];
    const float b2a  = (t < 264) ? vb2[s * RPS + t] : 0.0f;
    const float sc2a = (t < 264) ? scf[WS_SC2 + s * RPS + t] : 0.0f;
    const float b2b  = (t < 264) ? vb2[s * RPS + t + 264] : 0.0f;
    const float sc2b = (t < 264) ? scf[WS_SC2 + s * RPS + t + 264] : 0.0f;

    int budget = 1 << 16, flagged = 0;   // bail -> flag -> rescue kernel fixes out

    // stage W2 slice -> LDS [q][row] (inverse of prep tiling)
    for (int idx = t; idx < RPS * 64; idx += 1024) {
        int row = idx >> 6, w = idx & 63;
        int grow = s * RPS + row;
        int q = w >> 2, e = w & 3;
        s_w2[((q * RPS + row) << 2) + e] =
            wsb[WS_W2 + ((((grow >> 6) * 16 + q) * 64 + (grow & 63)) << 2) + e];
    }

    const int jx = t >> 6, cx = t & 63;
    const float* ysbx = ys + (size_t)(2 * g + (jx & 1)) * kT * kD;
    float x_reg = 0.0f, x_next = 0.0f;
    if (t < 128 && cx < kC) {
        x_reg  = (cx == 0) ? ts[0] : ysbx[cx - 1];
        x_next = (cx == 0) ? ts[1] : ysbx[kD + (cx - 1)];
        s_dx[0][jx][cx] = x_reg;
    }
    if (t < 2) { s_inp[t][65] = 0.0f; s_inp[t][66] = 0.0f; s_inp[t][67] = 0.0f; }
    __syncthreads();

    // ---- initial MLP (fp32, replicated across slices)
    {
        float acc = 0.0f;
        #pragma unroll
        for (int m = 0; m < 9; m++) {
            int c = k4_ + 4 * m;
            if (c < kC) acc += iW0[r_ * kC + c] * s_dx[0][jj_][c];
        }
        acc += __shfl_xor(acc, 1); acc += __shfl_xor(acc, 2);
        if (k4_ == 0) s_z1[jj_][r_] = fmaxf(ib0[r_] + acc, 0.0f);
    }
    __syncthreads();
    {
        float acc = 0.0f;
        #pragma unroll
        for (int m = 0; m < 32; m++) {
            int c = k4_ + 4 * m;
            acc += iW1[r_ * kW + c] * s_z1[jj_][c];
        }
        acc += __shfl_xor(acc, 1); acc += __shfl_xor(acc, 2);
        if (k4_ == 0) s_z2[jj_][r_] = fmaxf(ib1[r_] + acc, 0.0f);
    }
    __syncthreads();
    {
        int h = (t >> 3) & 63, k8 = t & 7;
        float acc = 0.0f;
        #pragma unroll
        for (int m = 0; m < 16; m++) {
            int c = k8 + 8 * m;
            acc += iW2[h * kW + c] * s_z2[jj_][c];
        }
        acc += __shfl_xor(acc, 1); acc += __shfl_xor(acc, 2); acc += __shfl_xor(acc, 4);
        if (k8 == 0) s_yt[jj_][h] = ib2[h] + acc;
    }
    __syncthreads();
    if (t < 32) {
        int j = t >> 4, hl = t & 15;
        float y0 = s_yt[j][16 * s + hl];
        s_y[j][hl] = y0; s_yh[j][hl] = y0;
    }
    if (t < 128) s_inp[t >> 6][1 + (t & 63)] = s_yt[t >> 6][t & 63];
    if (t < 2)   s_inp[t][0] = ts[0];
    __syncthreads();

    // ---- main scan
    for (int i = 0; i < kT; i++) {
        const int cur = i & 1;
        const int nxt = (i + 1) & 1;

        // layer 1: 65 -> 128, int16, split-k-4
        {
            float acc = 0.0f;
            const unsigned* rowp = wsW0 + r_ * 33;
            #pragma unroll
            for (int m = 0; m < 9; m++) {
                int p = k4_ + 4 * m;
                if (p < 33) {
                    float2 z = *(const float2*)&s_inp[jj_][2 * p];
                    acc = fma2i(rowp[p], z.x, z.y, acc);
                }
            }
            acc += __shfl_xor(acc, 1); acc += __shfl_xor(acc, 2);
            if (k4_ == 0) s_z1[jj_][r_] = lipswish_f(b0r + s0r * acc);
        }
        __syncthreads();
        // layer 2: 128 -> 128, int16
        {
            float acc = 0.0f;
            const unsigned* rowp = wsW1 + r_ * 64;
            #pragma unroll
            for (int m = 0; m < 16; m++) {
                int p = k4_ + 4 * m;
                float2 z = *(const float2*)&s_z1[jj_][2 * p];
                acc = fma2i(rowp[p], z.x, z.y, acc);
            }
            acc += __shfl_xor(acc, 1); acc += __shfl_xor(acc, 2);
            if (k4_ == 0) s_z2[jj_][r_] = lipswish_f(b1r + s1r * acc);
        }
        __syncthreads();
        // layer 3: 528 rows from LDS, both batches; 264 threads x 2 rows
        if (t < 264) {
            const uint4* wq4 = (const uint4*)s_w2;
            float a00 = 0.0f, a01 = 0.0f, a10 = 0.0f, a11 = 0.0f;
            #pragma unroll 4
            for (int q = 0; q < 16; q++) {
                const float4* z0p = (const float4*)&s_z2[0][8 * q];
                const float4* z1p = (const float4*)&s_z2[1][8 * q];
                float4 za0 = z0p[0], zb0 = z0p[1];
                float4 za1 = z1p[0], zb1 = z1p[1];
                uint4 w0 = wq4[q * RPS + t];
                uint4 w1 = wq4[q * RPS + t + 264];
                a00 = fma8i(w0, za0, zb0, a00);
                a01 = fma8i(w0, za1, zb1, a01);
                a10 = fma8i(w1, za0, zb0, a10);
                a11 = fma8i(w1, za1, zb1, a11);
            }
            s_v[0][t]       = fast_tanh(b2a + sc2a * a00);
            s_v[1][t]       = fast_tanh(b2a + sc2a * a01);
            s_v[0][t + 264] = fast_tanh(b2b + sc2b * a10);
            s_v[1][t + 264] = fast_tanh(b2b + sc2b * a11);
        }
        __syncthreads();

        // y-update (own 16 h's) || phase A dx
        if (i > 0 && t < 32) {
            int j = t >> 4, hl = t & 15;
            const float* vr = &s_v[j][hl * kC];
            float acc = 0.0f;
            #pragma unroll
            for (int c = 0; c < kC; c++) acc += vr[c] * s_dx[cur][j][c];
            s_y[j][hl] += 0.5f * (s_e[j][hl] + acc);
        }
        if (i < kT - 1 && t < 128 && cx < kC) {
            float xi = x_next;
            s_dx[nxt][jx][cx] = xi - x_reg;
            x_reg = xi;
            if (i + 2 < kT)
                x_next = (cx == 0) ? ts[i + 2] : ysbx[(size_t)(i + 2) * kD + (cx - 1)];
        }
        __syncthreads();

        if (i < kT - 1) {
            // phase B: e, yhat; tagged publish (epoch i+1) then tagged read
            unsigned tag = (unsigned)(i + 1);
            if (t < 32) {
                int j = t >> 4, hl = t & 15;
                const float* vr = &s_v[j][hl * kC];
                float e = 0.0f;
                #pragma unroll
                for (int c = 0; c < kC; c++) e += vr[c] * s_dx[nxt][j][c];
                s_e[j][hl] = e;
                float yh = 2.0f * s_y[j][hl] - s_yh[j][hl] + e;
                s_yh[j][hl] = yh;
                xput(xch + (((g * 4 + s) * 2 + nxt) << 5) + t, tag, yh);
            }
            if (t < 128) {
                int s2 = t >> 5, w = t & 31;
                float v = xget(xch + (((g * 4 + s2) * 2 + nxt) << 5) + w,
                               tag, budget, flagged, flagp);
                s_inp[w >> 4][1 + s2 * 16 + (w & 15)] = v;
            }
            if (t == 128) s_inp[0][0] = ts[i + 1];
            if (t == 129) s_inp[1][0] = ts[i + 1];
            __syncthreads();
        }
    }

    // final: tagged publish of y (tag kT, parity 0); slice 0 reduces & writes out
    if (t < 32) {
        int j = t >> 4, hl = t & 15;
        xput(xch + (((g * 4 + s) * 2 + 0) << 5) + t, (unsigned)kT, s_y[j][hl]);
    }
    if (s == 0) {
        if (t < 128) {
            int s2 = t >> 5, w = t & 31;
            float v = xget(xch + (((g * 4 + s2) * 2 + 0) << 5) + w,
                           (unsigned)kT, budget, flagged, flagp);
            s_yt[w >> 4][s2 * 16 + (w & 15)] = v;
        }
        __syncthreads();
        if (t < 2) {
            float acc = rb[0];
            #pragma unroll
            for (int h = 0; h < kH; h++) acc += s_yt[t][h] * rW[h];
            out[2 * g + t] = acc;
        }
    }
}

// ============ R4 streaming kernel (proven 6.45 ms); RESCUE => run only if flag set ============
template <int QI, int RESCUE>
__global__ __launch_bounds__(1024)
void cde_kernel(
    const float* __restrict__ ts,  const float* __restrict__ ys,
    const float* __restrict__ iW0, const float* __restrict__ ib0,
    const float* __restrict__ iW1, const float* __restrict__ ib1,
    const float* __restrict__ iW2, const float* __restrict__ ib2,
    const float* __restrict__ vW0, const float* __restrict__ vb0,
    const float* __restrict__ vW1, const float* __restrict__ vb1,
    const float* __restrict__ vW2, const float* __restrict__ vb2,
    const float* __restrict__ rW,  const float* __restrict__ rb,
    const unsigned* __restrict__ wsb,
    float* __restrict__ out)
{
    if (RESCUE && wsb[WS_FLAG] == 0u) return;   // fast path OK -> no-op

    const int b  = blockIdx.x;
    const int t  = threadIdx.x;
    const int r8 = t >> 3;
    const int g  = t & 7;
    const int wv = t >> 6;
    const int ln = t & 63;

    __shared__ __align__(16) float s_v[kO];
    __shared__ __align__(16) float s_z1[kW], s_z2[kW];
    __shared__ __align__(16) float s_inp[kIN + 1];
    __shared__ float s_y[kH], s_yhat[kH], s_e[kH];
    __shared__ float s_dx[kC];

    const float*    ysb   = ys + (size_t)b * kT * kD;
    const uint4*    wsW2q = (const uint4*)(wsb + WS_W2);
    const unsigned* wsW1  = wsb + WS_W1;
    const unsigned* wsW0  = wsb + WS_W0;
    const float*    scf   = (const float*)wsb;

    const float bA  = vb2[t];
    const float bB  = vb2[t + 1024];
    const float bTl = (t < 512) ? vb2[2048 + r8] : 0.0f;
    const float b0r = vb0[r8];
    const float b1r = vb1[r8];
    const float sA  = QI ? scf[WS_SC2 + t] : 0.0f;
    const float sB  = QI ? scf[WS_SC2 + t + 1024] : 0.0f;
    const float sTl = (QI && t < 512) ? scf[WS_SC2 + 2048 + r8] : 0.0f;
    const float s0r = QI ? scf[WS_SC0 + r8] : 0.0f;
    const float s1r = QI ? scf[WS_SC1 + r8] : 0.0f;

    float x_reg = 0.0f, x_next = 0.0f;
    if (t < kC) {
        x_reg  = (t == 0) ? ts[0] : ysb[t - 1];
        x_next = (t == 0) ? ts[1] : ysb[kD + (t - 1)];
        s_dx[t] = x_reg;
    }
    if (t == 0) s_inp[kIN] = 0.0f;
    __syncthreads();

    if (t < kW) {
        const float* wrow = iW0 + t * kC;
        float acc = ib0[t];
        #pragma unroll
        for (int c = 0; c < kC; c++) acc += wrow[c] * s_dx[c];
        s_z1[t] = fmaxf(acc, 0.0f);
    }
    __syncthreads();
    if (t < kW) {
        const float4* wr = (const float4*)(iW1 + t * kW);
        const float4* z4 = (const float4*)s_z1;
        float acc = ib1[t];
        #pragma unroll 8
        for (int q = 0; q < kW / 4; q++) acc += dot4(wr[q], z4[q]);
        s_z2[t] = fmaxf(acc, 0.0f);
    }
    __syncthreads();
    if (t < kH) {
        const float4* wr = (const float4*)(iW2 + t * kW);
        const float4* z4 = (const float4*)s_z2;
        float acc = ib2[t];
        #pragma unroll 8
        for (int q = 0; q < kW / 4; q++) acc += dot4(wr[q], z4[q]);
        s_y[t] = acc; s_yhat[t] = acc;
        s_inp[1 + t] = acc;
    }
    if (t == 0) s_inp[0] = x_reg;
    __syncthreads();

    for (int i = 0; i < kT; i++) {
        {
            float acc = 0.0f;
            if (QI) {
                const unsigned* rowp = wsW0 + r8 * 33;
                #pragma unroll
                for (int m = 0; m < 5; m++) {
                    int p = g + 8 * m;
                    if (p < 33) acc = fma2i(rowp[p], s_inp[2 * p], s_inp[2 * p + 1], acc);
                }
            } else {
                const float* rowp = vW0 + r8 * kIN;
                #pragma unroll
                for (int m = 0; m < 5; m++) {
                    int p = g + 8 * m;
                    if (p < 33) {
                        float w0 = rowp[2 * p];
                        float w1 = (2 * p + 1 < kIN) ? rowp[2 * p + 1] : 0.0f;
                        acc += w0 * s_inp[2 * p] + w1 * s_inp[2 * p + 1];
                    }
                }
            }
            acc += __shfl_xor(acc, 1);
            acc += __shfl_xor(acc, 2);
            acc += __shfl_xor(acc, 4);
            if (g == 0) s_z1[r8] = lipswish_f(b0r + (QI ? s0r * acc : acc));
        }
        __syncthreads();
        {
            float acc = 0.0f;
            #pragma unroll
            for (int m = 0; m < 2; m++) {
                int ch = g + 8 * m;
                int c0 = 8 * ch;
                const float4* z4 = (const float4*)(s_z1 + c0);
                float4 za = z4[0], zb = z4[1];
                if (QI) {
                    uint4 u = *(const uint4*)(wsW1 + r8 * 64 + 4 * ch);
                    acc = fma8i(u, za, zb, acc);
                } else {
                    const float* wr = vW1 + r8 * kW + c0;
                    acc += dot4(*(const float4*)wr, za) + dot4(*(const float4*)(wr + 4), zb);
                }
            }
            acc += __shfl_xor(acc, 1);
            acc += __shfl_xor(acc, 2);
            acc += __shfl_xor(acc, 4);
            if (g == 0) s_z2[r8] = lipswish_f(b1r + (QI ? s1r * acc : acc));
        }
        __syncthreads();
        {
            float acc0 = 0.0f, acc1 = 0.0f;
            if (QI) {
                const uint4* pA = wsW2q + (size_t)(wv * 16) * 64 + ln;
                const uint4* pB = wsW2q + (size_t)((wv + 16) * 16) * 64 + ln;
                #pragma unroll 2
                for (int m = 0; m < 8; m++) {
                    const float4* z4 = (const float4*)(s_z2 + 16 * m);
                    float4 z0 = z4[0], z1 = z4[1], z2 = z4[2], z3 = z4[3];
                    uint4 a0 = pA[(2 * m) * 64], a1 = pA[(2 * m + 1) * 64];
                    uint4 c0 = pB[(2 * m) * 64], c1 = pB[(2 * m + 1) * 64];
                    acc0 = fma8i(a0, z0, z1, acc0);
                    acc0 = fma8i(a1, z2, z3, acc0);
                    acc1 = fma8i(c0, z0, z1, acc1);
                    acc1 = fma8i(c1, z2, z3, acc1);
                }
                s_v[t]        = fast_tanh(bA + sA * acc0);
                s_v[t + 1024] = fast_tanh(bB + sB * acc1);
            } else {
                #pragma unroll 2
                for (int m = 0; m < 8; m++) {
                    const float4* z4 = (const float4*)(s_z2 + 16 * m);
                    float4 z0 = z4[0], z1 = z4[1], z2 = z4[2], z3 = z4[3];
                    const float4* rA = (const float4*)(vW2 + (size_t)t * kW + 16 * m);
                    const float4* rB = (const float4*)(vW2 + (size_t)(t + 1024) * kW + 16 * m);
                    acc0 += dot4(rA[0], z0) + dot4(rA[1], z1) + dot4(rA[2], z2) + dot4(rA[3], z3);
                    acc1 += dot4(rB[0], z0) + dot4(rB[1], z1) + dot4(rB[2], z2) + dot4(rB[3], z3);
                }
                s_v[t]        = fast_tanh(bA + acc0);
                s_v[t + 1024] = fast_tanh(bB + acc1);
            }
        }
        if (t < 512) {
            int c0i = 16 * g;
            const float4* z4 = (const float4*)(s_z2 + c0i);
            float4 z0 = z4[0], z1 = z4[1], z2 = z4[2], z3 = z4[3];
            float acc = 0.0f;
            if (QI) {
                uint4 u0 = wsW2q[(size_t)(32 * 16 + 2 * g) * 64 + r8];
                uint4 u1 = wsW2q[(size_t)(32 * 16 + 2 * g + 1) * 64 + r8];
                acc = fma8i(u0, z0, z1, acc);
                acc = fma8i(u1, z2, z3, acc);
            } else {
                const float4* wr = (const float4*)(vW2 + (size_t)(2048 + r8) * kW + c0i);
                acc += dot4(wr[0], z0) + dot4(wr[1], z1) + dot4(wr[2], z2) + dot4(wr[3], z3);
            }
            acc += __shfl_xor(acc, 1);
            acc += __shfl_xor(acc, 2);
            acc += __shfl_xor(acc, 4);
            if (g == 0) s_v[2048 + r8] = fast_tanh(bTl + (QI ? sTl * acc : acc));
        }
        __syncthreads();

        if (i > 0 && t < kH) {
            const float* vr = s_v + t * kC;
            float acc = 0.0f;
            #pragma unroll
            for (int c = 0; c < kC; c++) acc += vr[c] * s_dx[c];
            s_y[t] += 0.5f * (s_e[t] + acc);
        }
        __syncthreads();

        if (i < kT - 1) {
            if (t < kC) {
                float xi = x_next;
                s_dx[t] = xi - x_reg;
                x_reg = xi;
                if (i + 2 < kT)
                    x_next = (t == 0) ? ts[i + 2] : ysb[(size_t)(i + 2) * kD + (t - 1)];
            }
            __syncthreads();
            if (t < kH) {
                const float* vr = s_v + t * kC;
                float e = 0.0f;
                #pragma unroll
                for (int c = 0; c < kC; c++) e += vr[c] * s_dx[c];
                s_e[t] = e;
                float yh = 2.0f * s_y[t] - s_yhat[t] + e;
                s_yhat[t] = yh;
                s_inp[1 + t] = yh;
            }
            if (t == 0) s_inp[0] = x_reg;
            __syncthreads();
        }
    }

    __syncthreads();
    if (t == 0) {
        float acc = rb[0];
        #pragma unroll
        for (int h = 0; h < kH; h++) acc += s_y[h] * rW[h];
        out[b] = acc;
    }
}

extern "C" void kernel_launch(void* const* d_in, const int* in_sizes, int n_in,
                              void* d_out, int out_size, void* d_ws, size_t ws_size,
                              hipStream_t stream)
{
    const float* ts  = (const float*)d_in[0];
    const float* ys  = (const float*)d_in[1];
    const float* iW0 = (const float*)d_in[2];
    const float* ib0 = (const float*)d_in[3];
    const float* iW1 = (const float*)d_in[4];
    const float* ib1 = (const float*)d_in[5];
    const float* iW2 = (const float*)d_in[6];
    const float* ib2 = (const float*)d_in[7];
    const float* vW0 = (const float*)d_in[8];
    const float* vb0 = (const float*)d_in[9];
    const float* vW1 = (const float*)d_in[10];
    const float* vb1 = (const float*)d_in[11];
    const float* vW2 = (const float*)d_in[12];
    const float* vb2 = (const float*)d_in[13];
    const float* rW  = (const float*)d_in[14];
    const float* rb  = (const float*)d_in[15];
    float* out = (float*)d_out;
    unsigned* ws = (unsigned*)d_ws;

    constexpr unsigned kDynLds = 16 * RPS * 16;   // 135,168 B

    if (ws_size >= (size_t)WS_TOT * 4) {
        hipLaunchKernelGGL(prep_kernel, dim3(kO + kW + kW), dim3(64), 0, stream,
                           vW0, vW1, vW2, ws, 1);
        (void)hipFuncSetAttribute(reinterpret_cast<const void*>(cde_sliced),
                                  hipFuncAttributeMaxDynamicSharedMemorySize,
                                  (int)kDynLds);
        hipLaunchKernelGGL(cde_sliced, dim3(256), dim3(1024), kDynLds, stream,
                           ts, ys, iW0, ib0, iW1, ib1, iW2, ib2,
                           vb0, vb1, vb2, rW, rb, ws, out);
        // rescue: no-op if the sliced exchange completed without a bail
        hipLaunchKernelGGL((cde_kernel<1, 1>), dim3(kB), dim3(1024), 0, stream,
                           ts, ys, iW0, ib0, iW1, ib1, iW2, ib2,
                           vW0, vb0, vW1, vb1, vW2, vb2, rW, rb, ws, out);
    } else if (ws_size >= (size_t)WS_R4TOT * 4) {
        hipLaunchKernelGGL(prep_kernel, dim3(kO + kW + kW), dim3(64), 0, stream,
                           vW0, vW1, vW2, ws, 0);
        hipLaunchKernelGGL((cde_kernel<1, 0>), dim3(kB), dim3(1024), 0, stream,
                           ts, ys, iW0, ib0, iW1, ib1, iW2, ib2,
                           vW0, vb0, vW1, vb1, vW2, vb2, rW, rb, ws, out);
    } else {
        hipLaunchKernelGGL((cde_kernel<0, 0>), dim3(kB), dim3(1024), 0, stream,
                           ts, ys, iW0, ib0, iW1, ib1, iW2, ib2,
                           vW0, vb0, vW1, vb1, vW2, vb2, rW, rb, ws, out);
    }
}